// Round 2
// baseline (676.839 us; speedup 1.0000x reference)
//
#include <hip/hip_runtime.h>
#include <hip/hip_bf16.h>

typedef __hip_bfloat16 bf16;
typedef __attribute__((ext_vector_type(8))) short short8;
typedef __attribute__((ext_vector_type(4))) float f32x4;

#define MFMA16(a, b, c) __builtin_amdgcn_mfma_f32_16x16x32_bf16((a), (b), (c), 0, 0, 0)

typedef const __attribute__((address_space(1))) void GVOID;
typedef __attribute__((address_space(3))) void LVOID;

__device__ __forceinline__ float b2f(short s) {
    union { unsigned u; float f; } v;
    v.u = ((unsigned)(unsigned short)s) << 16;
    return v.f;
}
__device__ __forceinline__ short f2b(float f) {
    union { float f; unsigned u; } v;
    v.f = f;
    unsigned r = v.u + 0x7fffu + ((v.u >> 16) & 1u);
    return (short)(r >> 16);
}

// ---------------------------------------------------------------------------
// Dtype sniffer. If the input buffer holds f32 data, the LOW half of each
// 32-bit word is random mantissa bits -> bf16 exponent field uniform in
// 0..255 (~45% > 140). If it holds packed bf16 N(0,1) data, exponent <= ~131.
// flag = 1 -> inputs are f32; flag = 0 -> inputs are bf16.
// ---------------------------------------------------------------------------
__global__ void sniff_kernel(const unsigned* __restrict__ X, int* __restrict__ flag) {
    __shared__ int cnt;
    if (threadIdx.x == 0) cnt = 0;
    __syncthreads();
    int c = 0;
    for (int i = threadIdx.x; i < 256; i += 64) {
        unsigned w = X[i];
        unsigned e = (w >> 7) & 0xFFu;  // exponent field of low-half bf16
        c += (e > 140u) ? 1 : 0;
    }
    atomicAdd(&cnt, c);
    __syncthreads();
    if (threadIdx.x == 0) *flag = (cnt >= 16) ? 1 : 0;
}

// Canonicalize a matrix to bf16 (8 elements per thread).
__global__ __launch_bounds__(256) void canon_bf16_kernel(
    const void* __restrict__ src, short* __restrict__ dst, int n8,
    const int* __restrict__ flag)
{
    int i = blockIdx.x * 256 + threadIdx.x;
    if (i >= n8) return;
    short8 o;
    if (*flag) {
        const float* s = (const float*)src + (size_t)i * 8;
#pragma unroll
        for (int j = 0; j < 8; ++j) o[j] = f2b(s[j]);
    } else {
        o = ((const short8*)src)[i];
    }
    ((short8*)dst)[i] = o;
}

// Canonicalize a small vector to f32.
__global__ void canon_f32_kernel(
    const void* __restrict__ src, float* __restrict__ dst, int n,
    const int* __restrict__ flag)
{
    int i = blockIdx.x * 256 + threadIdx.x;
    if (i >= n) return;
    dst[i] = (*flag) ? ((const float*)src)[i] : b2f(((const short*)src)[i]);
}

// ---------------------------------------------------------------------------
// RoPE tables: cos/sin [1024][96] fp32.
// ---------------------------------------------------------------------------
__global__ void rope_tables_kernel(float* __restrict__ cosT, float* __restrict__ sinT) {
    int idx = blockIdx.x * 256 + threadIdx.x;
    if (idx >= 1024 * 96) return;
    int p = idx / 96;
    int d = idx - p * 96;
    int r = p >> 5, c = p & 31;
    int inRow = (d < 48);
    int dd = inRow ? d : d - 48;
    float pos = inRow ? (float)r : (float)c;
    float ex = -(float)(dd & ~1) / 48.0f;
    float f = powf(10000.0f, ex);
    float ang = pos * f;
    cosT[idx] = cosf(ang);
    sinT[idx] = sinf(ang);
}

// ---------------------------------------------------------------------------
// NT GEMM + bias: C[M,N] = A[M,K] * B[N,K]^T + bias[N]. bf16 in, fp32 acc.
// Output bf16, or f32 when outFlag != nullptr and *outFlag == 1.
// 128x128 tile, BK=32, 4 waves, global_load_lds staging, 16x16x32 MFMA.
// ---------------------------------------------------------------------------
__global__ __launch_bounds__(256) void gemm_bias_kernel(
    const bf16* __restrict__ A, const bf16* __restrict__ B,
    const float* __restrict__ bias, void* __restrict__ C,
    int M, int N, int K, const int* __restrict__ outFlag)
{
    __shared__ __align__(16) short As[128 * 32];
    __shared__ __align__(16) short Bs[128 * 32];

    const int tid = threadIdx.x;
    const int l  = tid & 63;
    const int w  = tid >> 6;
    const int wr = w >> 1, wc = w & 1;
    const int li = l & 15, lg = l >> 4;
    const long mBase = (long)blockIdx.y * 128;
    const long nBase = (long)blockIdx.x * 128;

    const int srow = tid >> 2;
    const int scol = (tid & 3) * 8;
    const bf16* ga0 = A + (mBase + srow) * K + scol;
    const bf16* ga1 = A + (mBase + 64 + srow) * K + scol;
    const bf16* gb0 = B + (nBase + srow) * K + scol;
    const bf16* gb1 = B + (nBase + 64 + srow) * K + scol;
    short* la0 = &As[srow * 32 + scol];
    short* la1 = &As[(64 + srow) * 32 + scol];
    short* lb0 = &Bs[srow * 32 + scol];
    short* lb1 = &Bs[(64 + srow) * 32 + scol];

    f32x4 acc[4][4] = {};

    for (int k0 = 0; k0 < K; k0 += 32) {
        __builtin_amdgcn_global_load_lds((GVOID*)(ga0 + k0), (LVOID*)la0, 16, 0, 0);
        __builtin_amdgcn_global_load_lds((GVOID*)(ga1 + k0), (LVOID*)la1, 16, 0, 0);
        __builtin_amdgcn_global_load_lds((GVOID*)(gb0 + k0), (LVOID*)lb0, 16, 0, 0);
        __builtin_amdgcn_global_load_lds((GVOID*)(gb1 + k0), (LVOID*)lb1, 16, 0, 0);
        __syncthreads();

        short8 fa[4], fb[4];
#pragma unroll
        for (int m = 0; m < 4; ++m)
            fa[m] = *(const short8*)&As[(wr * 64 + m * 16 + li) * 32 + lg * 8];
#pragma unroll
        for (int n = 0; n < 4; ++n)
            fb[n] = *(const short8*)&Bs[(wc * 64 + n * 16 + li) * 32 + lg * 8];
#pragma unroll
        for (int m = 0; m < 4; ++m)
#pragma unroll
            for (int n = 0; n < 4; ++n)
                acc[m][n] = MFMA16(fa[m], fb[n], acc[m][n]);
        __syncthreads();
    }

    const int f32out = outFlag ? *outFlag : 0;
    if (f32out) {
        float* Cf = (float*)C;
#pragma unroll
        for (int n = 0; n < 4; ++n) {
            const long col = nBase + wc * 64 + n * 16 + li;
            const float bv = bias[col];
#pragma unroll
            for (int m = 0; m < 4; ++m) {
                const long row = mBase + wr * 64 + m * 16 + lg * 4;
#pragma unroll
                for (int i = 0; i < 4; ++i)
                    Cf[(row + i) * N + col] = acc[m][n][i] + bv;
            }
        }
    } else {
        bf16* Cb = (bf16*)C;
#pragma unroll
        for (int n = 0; n < 4; ++n) {
            const long col = nBase + wc * 64 + n * 16 + li;
            const float bv = bias[col];
#pragma unroll
            for (int m = 0; m < 4; ++m) {
                const long row = mBase + wr * 64 + m * 16 + lg * 4;
#pragma unroll
                for (int i = 0; i < 4; ++i)
                    Cb[(row + i) * N + col] = __float2bfloat16(acc[m][n][i] + bv);
            }
        }
    }
}

// ---------------------------------------------------------------------------
// Fused per-head RMSNorm + RoPE, in place. One thread = one (token, head) row.
// ---------------------------------------------------------------------------
__global__ __launch_bounds__(256) void norm_rope_kernel(
    bf16* __restrict__ T, const float* __restrict__ wgt,
    const float* __restrict__ cosT, const float* __restrict__ sinT,
    float scale)
{
    const int row = blockIdx.x * 256 + threadIdx.x;
    const int tok = row >> 4;
    const int h = row & 15;
    const int spos = tok & 1023;
    bf16* p = T + (size_t)tok * 1536 + h * 96;

    float x[96];
#pragma unroll
    for (int v = 0; v < 12; ++v) {
        short8 t = *(const short8*)(p + v * 8);
#pragma unroll
        for (int j = 0; j < 8; ++j) x[v * 8 + j] = b2f(t[j]);
    }
    float ss = 0.f;
#pragma unroll
    for (int d = 0; d < 96; ++d) ss += x[d] * x[d];
    const float rn = scale / sqrtf(ss * (1.0f / 96.0f) + 1e-6f);

    const float* cr = cosT + spos * 96;
    const float* sr = sinT + spos * 96;

#pragma unroll
    for (int v = 0; v < 12; ++v) {
        short8 o;
#pragma unroll
        for (int j = 0; j < 8; j += 2) {
            const int d = v * 8 + j;
            const float x0 = x[d] * rn * wgt[d];
            const float x1 = x[d + 1] * rn * wgt[d + 1];
            o[j]     = f2b(x0 * cr[d] - x1 * sr[d]);
            o[j + 1] = f2b(x1 * cr[d + 1] + x0 * sr[d + 1]);
        }
        *(short8*)(p + v * 8) = o;
    }
}

// ---------------------------------------------------------------------------
// Flash attention: block = one (b,h) x 64 Q rows (4 waves x 16).
// ---------------------------------------------------------------------------
__global__ __launch_bounds__(256) void attn_kernel(
    const bf16* __restrict__ Q, const bf16* __restrict__ K,
    const bf16* __restrict__ V, bf16* __restrict__ O)
{
    __shared__ __align__(16) short Vt[96 * 64];
    __shared__ __align__(16) short Pl[4][16 * 64];

    const int tid = threadIdx.x;
    const int l = tid & 63, w = tid >> 6;
    const int li = l & 15, lg = l >> 4;
    const int qt = blockIdx.x & 15;
    const int bh = blockIdx.x >> 4;
    const int b = bh >> 4, h = bh & 15;

    const bf16* qp = Q + (size_t)(b * 1024 + qt * 64 + w * 16 + li) * 1536 + h * 96;
    short8 aq[3];
#pragma unroll
    for (int kk = 0; kk < 3; ++kk)
        aq[kk] = *(const short8*)(qp + kk * 32 + lg * 8);

    float m_r[4], l_r[4];
#pragma unroll
    for (int i = 0; i < 4; ++i) { m_r[i] = -1e30f; l_r[i] = 0.f; }
    f32x4 o[6] = {};

    const int vrow = tid >> 2;
    const int vc0 = (tid & 3) * 24;
    short* Plw = &Pl[w][0];

    for (int t0 = 0; t0 < 1024; t0 += 64) {
        __syncthreads();
        const bf16* vp = V + (size_t)(b * 1024 + t0 + vrow) * 1536 + h * 96 + vc0;
#pragma unroll
        for (int u = 0; u < 3; ++u) {
            short8 t = *(const short8*)(vp + u * 8);
#pragma unroll
            for (int j = 0; j < 8; ++j)
                Vt[(vc0 + u * 8 + j) * 64 + vrow] = t[j];
        }
        __syncthreads();

        f32x4 s4[4] = {};
#pragma unroll
        for (int kn = 0; kn < 4; ++kn) {
            const bf16* kp = K + (size_t)(b * 1024 + t0 + kn * 16 + li) * 1536 + h * 96;
#pragma unroll
            for (int kk = 0; kk < 3; ++kk) {
                short8 fb = *(const short8*)(kp + kk * 32 + lg * 8);
                s4[kn] = MFMA16(aq[kk], fb, s4[kn]);
            }
        }

        float ps[4][4];
#pragma unroll
        for (int i = 0; i < 4; ++i) {
            float pm = fmaxf(fmaxf(s4[0][i], s4[1][i]), fmaxf(s4[2][i], s4[3][i]));
#pragma unroll
            for (int msk = 1; msk < 16; msk <<= 1)
                pm = fmaxf(pm, __shfl_xor(pm, msk));
            const float mn = fmaxf(m_r[i], pm);
            const float alpha = __expf(m_r[i] - mn);
            m_r[i] = mn;
            float rs = 0.f;
#pragma unroll
            for (int kn = 0; kn < 4; ++kn) {
                const float pv = __expf(s4[kn][i] - mn);
                ps[kn][i] = pv;
                rs += pv;
            }
#pragma unroll
            for (int msk = 1; msk < 16; msk <<= 1)
                rs += __shfl_xor(rs, msk);
            l_r[i] = l_r[i] * alpha + rs;
#pragma unroll
            for (int dn = 0; dn < 6; ++dn) o[dn][i] *= alpha;
        }

#pragma unroll
        for (int kn = 0; kn < 4; ++kn)
#pragma unroll
            for (int i = 0; i < 4; ++i)
                Plw[(lg * 4 + i) * 64 + kn * 16 + li] = f2b(ps[kn][i]);

#pragma unroll
        for (int kt = 0; kt < 2; ++kt) {
            short8 pa = *(const short8*)&Plw[li * 64 + kt * 32 + lg * 8];
#pragma unroll
            for (int dn = 0; dn < 6; ++dn) {
                short8 fv = *(const short8*)&Vt[(dn * 16 + li) * 64 + kt * 32 + lg * 8];
                o[dn] = MFMA16(pa, fv, o[dn]);
            }
        }
    }

#pragma unroll
    for (int dn = 0; dn < 6; ++dn)
#pragma unroll
        for (int i = 0; i < 4; ++i) {
            const size_t row = (size_t)(b * 1024 + qt * 64 + w * 16 + lg * 4 + i);
            O[row * 1536 + h * 96 + dn * 16 + li] = __float2bfloat16(o[dn][i] / l_r[i]);
        }
}

// ---------------------------------------------------------------------------
extern "C" void kernel_launch(void* const* d_in, const int* in_sizes, int n_in,
                              void* d_out, int out_size, void* d_ws, size_t ws_size,
                              hipStream_t stream) {
    const void* X  = d_in[0];
    const void* Wq = d_in[1];
    const void* bq = d_in[2];
    const void* Wk = d_in[3];
    const void* bk = d_in[4];
    const void* Wv = d_in[5];
    const void* bv = d_in[6];
    const void* qw = d_in[7];
    const void* kw = d_in[8];
    const void* Wo = d_in[9];
    const void* bo = d_in[10];

    char* ws = (char*)d_ws;
    size_t off = 0;
    int* flag = (int*)ws;                      off += 256;
    float* cosT = (float*)(ws + off);          off += 1024 * 96 * 4;
    float* sinT = (float*)(ws + off);          off += 1024 * 96 * 4;
    float* bqc  = (float*)(ws + off);          off += 1536 * 4;
    float* bkc  = (float*)(ws + off);          off += 1536 * 4;
    float* bvc  = (float*)(ws + off);          off += 1536 * 4;
    float* boc  = (float*)(ws + off);          off += 1536 * 4;
    float* qwc  = (float*)(ws + off);          off += 128 * 4;
    float* kwc  = (float*)(ws + off);          off += 128 * 4;
    off = (off + 255) & ~(size_t)255;
    bf16* Wqc = (bf16*)(ws + off);             off += (size_t)1536 * 1536 * 2;
    bf16* Wkc = (bf16*)(ws + off);             off += (size_t)1536 * 1536 * 2;
    bf16* Wvc = (bf16*)(ws + off);             off += (size_t)1536 * 1536 * 2;
    bf16* Woc = (bf16*)(ws + off);             off += (size_t)1536 * 1536 * 2;
    bf16* Xc  = (bf16*)(ws + off);             off += (size_t)8192 * 1536 * 2;  // reused as AO
    bf16* Qb  = (bf16*)(ws + off);             off += (size_t)8192 * 1536 * 2;
    bf16* Kb  = (bf16*)(ws + off);             off += (size_t)8192 * 1536 * 2;
    bf16* Vb  = (bf16*)(ws + off);             off += (size_t)8192 * 1536 * 2;
    bf16* AO  = Xc;

    sniff_kernel<<<1, 64, 0, stream>>>((const unsigned*)X, flag);

    const int nX8 = 8192 * 1536 / 8, nW8 = 1536 * 1536 / 8;
    canon_bf16_kernel<<<(nX8 + 255) / 256, 256, 0, stream>>>(X,  (short*)Xc,  nX8, flag);
    canon_bf16_kernel<<<(nW8 + 255) / 256, 256, 0, stream>>>(Wq, (short*)Wqc, nW8, flag);
    canon_bf16_kernel<<<(nW8 + 255) / 256, 256, 0, stream>>>(Wk, (short*)Wkc, nW8, flag);
    canon_bf16_kernel<<<(nW8 + 255) / 256, 256, 0, stream>>>(Wv, (short*)Wvc, nW8, flag);
    canon_bf16_kernel<<<(nW8 + 255) / 256, 256, 0, stream>>>(Wo, (short*)Woc, nW8, flag);
    canon_f32_kernel<<<6, 256, 0, stream>>>(bq, bqc, 1536, flag);
    canon_f32_kernel<<<6, 256, 0, stream>>>(bk, bkc, 1536, flag);
    canon_f32_kernel<<<6, 256, 0, stream>>>(bv, bvc, 1536, flag);
    canon_f32_kernel<<<6, 256, 0, stream>>>(bo, boc, 1536, flag);
    canon_f32_kernel<<<1, 256, 0, stream>>>(qw, qwc, 96, flag);
    canon_f32_kernel<<<1, 256, 0, stream>>>(kw, kwc, 96, flag);

    rope_tables_kernel<<<384, 256, 0, stream>>>(cosT, sinT);

    gemm_bias_kernel<<<dim3(12, 64), 256, 0, stream>>>(Xc, Wqc, bqc, Qb, 8192, 1536, 1536, nullptr);
    gemm_bias_kernel<<<dim3(12, 64), 256, 0, stream>>>(Xc, Wkc, bkc, Kb, 8192, 1536, 1536, nullptr);
    gemm_bias_kernel<<<dim3(12, 64), 256, 0, stream>>>(Xc, Wvc, bvc, Vb, 8192, 1536, 1536, nullptr);

    norm_rope_kernel<<<512, 256, 0, stream>>>(Qb, qwc, cosT, sinT, 0.10206207261596577f);
    norm_rope_kernel<<<512, 256, 0, stream>>>(Kb, kwc, cosT, sinT, 1.0f);

    attn_kernel<<<2048, 256, 0, stream>>>(Qb, Kb, Vb, AO);

    gemm_bias_kernel<<<dim3(12, 64), 256, 0, stream>>>(AO, Woc, boc, d_out, 8192, 1536, 1536, flag);
}

// Round 3
// 525.819 us; speedup vs baseline: 1.2872x; 1.2872x over previous
//
#include <hip/hip_runtime.h>
#include <hip/hip_bf16.h>

typedef __hip_bfloat16 bf16;
typedef __attribute__((ext_vector_type(8))) short short8;
typedef __attribute__((ext_vector_type(4))) float f32x4;

#define MFMA16(a, b, c) __builtin_amdgcn_mfma_f32_16x16x32_bf16((a), (b), (c), 0, 0, 0)

typedef const __attribute__((address_space(1))) void GVOID;
typedef __attribute__((address_space(3))) void LVOID;

__device__ __forceinline__ float b2f(short s) {
    union { unsigned u; float f; } v;
    v.u = ((unsigned)(unsigned short)s) << 16;
    return v.f;
}
__device__ __forceinline__ short f2b(float f) {
    union { float f; unsigned u; } v;
    v.f = f;
    unsigned r = v.u + 0x7fffu + ((v.u >> 16) & 1u);
    return (short)(r >> 16);
}

// ---------------------------------------------------------------------------
// Dtype sniffer (inputs are f32 per round-2 evidence, but keep the guard:
// deterministic, costs ~2us).
// ---------------------------------------------------------------------------
__global__ void sniff_kernel(const unsigned* __restrict__ X, int* __restrict__ flag) {
    __shared__ int cnt;
    if (threadIdx.x == 0) cnt = 0;
    __syncthreads();
    int c = 0;
    for (int i = threadIdx.x; i < 256; i += 64) {
        unsigned w = X[i];
        unsigned e = (w >> 7) & 0xFFu;
        c += (e > 140u) ? 1 : 0;
    }
    atomicAdd(&cnt, c);
    __syncthreads();
    if (threadIdx.x == 0) *flag = (cnt >= 16) ? 1 : 0;
}

__global__ __launch_bounds__(256) void canon_bf16_kernel(
    const void* __restrict__ src, short* __restrict__ dst, int n8,
    const int* __restrict__ flag)
{
    int i = blockIdx.x * 256 + threadIdx.x;
    if (i >= n8) return;
    short8 o;
    if (*flag) {
        const float* s = (const float*)src + (size_t)i * 8;
#pragma unroll
        for (int j = 0; j < 8; ++j) o[j] = f2b(s[j]);
    } else {
        o = ((const short8*)src)[i];
    }
    ((short8*)dst)[i] = o;
}

__global__ void canon_f32_kernel(
    const void* __restrict__ src, float* __restrict__ dst, int n,
    const int* __restrict__ flag)
{
    int i = blockIdx.x * 256 + threadIdx.x;
    if (i >= n) return;
    dst[i] = (*flag) ? ((const float*)src)[i] : b2f(((const short*)src)[i]);
}

// ---------------------------------------------------------------------------
// RoPE tables: cos/sin [1024][96] fp32.
// ---------------------------------------------------------------------------
__global__ void rope_tables_kernel(float* __restrict__ cosT, float* __restrict__ sinT) {
    int idx = blockIdx.x * 256 + threadIdx.x;
    if (idx >= 1024 * 96) return;
    int p = idx / 96;
    int d = idx - p * 96;
    int r = p >> 5, c = p & 31;
    int inRow = (d < 48);
    int dd = inRow ? d : d - 48;
    float pos = inRow ? (float)r : (float)c;
    float ex = -(float)(dd & ~1) / 48.0f;
    float f = powf(10000.0f, ex);
    float ang = pos * f;
    cosT[idx] = cosf(ang);
    sinT[idx] = sinf(ang);
}

// ---------------------------------------------------------------------------
// NT GEMM + bias (unchanged from round 2; GEMMs are the next-round target).
// ---------------------------------------------------------------------------
__global__ __launch_bounds__(256) void gemm_bias_kernel(
    const bf16* __restrict__ A, const bf16* __restrict__ B,
    const float* __restrict__ bias, void* __restrict__ C,
    int M, int N, int K, const int* __restrict__ outFlag)
{
    __shared__ __align__(16) short As[128 * 32];
    __shared__ __align__(16) short Bs[128 * 32];

    const int tid = threadIdx.x;
    const int l  = tid & 63;
    const int w  = tid >> 6;
    const int wr = w >> 1, wc = w & 1;
    const int li = l & 15, lg = l >> 4;
    const long mBase = (long)blockIdx.y * 128;
    const long nBase = (long)blockIdx.x * 128;

    const int srow = tid >> 2;
    const int scol = (tid & 3) * 8;
    const bf16* ga0 = A + (mBase + srow) * K + scol;
    const bf16* ga1 = A + (mBase + 64 + srow) * K + scol;
    const bf16* gb0 = B + (nBase + srow) * K + scol;
    const bf16* gb1 = B + (nBase + 64 + srow) * K + scol;
    short* la0 = &As[srow * 32 + scol];
    short* la1 = &As[(64 + srow) * 32 + scol];
    short* lb0 = &Bs[srow * 32 + scol];
    short* lb1 = &Bs[(64 + srow) * 32 + scol];

    f32x4 acc[4][4] = {};

    for (int k0 = 0; k0 < K; k0 += 32) {
        __builtin_amdgcn_global_load_lds((GVOID*)(ga0 + k0), (LVOID*)la0, 16, 0, 0);
        __builtin_amdgcn_global_load_lds((GVOID*)(ga1 + k0), (LVOID*)la1, 16, 0, 0);
        __builtin_amdgcn_global_load_lds((GVOID*)(gb0 + k0), (LVOID*)lb0, 16, 0, 0);
        __builtin_amdgcn_global_load_lds((GVOID*)(gb1 + k0), (LVOID*)lb1, 16, 0, 0);
        __syncthreads();

        short8 fa[4], fb[4];
#pragma unroll
        for (int m = 0; m < 4; ++m)
            fa[m] = *(const short8*)&As[(wr * 64 + m * 16 + li) * 32 + lg * 8];
#pragma unroll
        for (int n = 0; n < 4; ++n)
            fb[n] = *(const short8*)&Bs[(wc * 64 + n * 16 + li) * 32 + lg * 8];
#pragma unroll
        for (int m = 0; m < 4; ++m)
#pragma unroll
            for (int n = 0; n < 4; ++n)
                acc[m][n] = MFMA16(fa[m], fb[n], acc[m][n]);
        __syncthreads();
    }

    const int f32out = outFlag ? *outFlag : 0;
    if (f32out) {
        float* Cf = (float*)C;
#pragma unroll
        for (int n = 0; n < 4; ++n) {
            const long col = nBase + wc * 64 + n * 16 + li;
            const float bv = bias[col];
#pragma unroll
            for (int m = 0; m < 4; ++m) {
                const long row = mBase + wr * 64 + m * 16 + lg * 4;
#pragma unroll
                for (int i = 0; i < 4; ++i)
                    Cf[(row + i) * N + col] = acc[m][n][i] + bv;
            }
        }
    } else {
        bf16* Cb = (bf16*)C;
#pragma unroll
        for (int n = 0; n < 4; ++n) {
            const long col = nBase + wc * 64 + n * 16 + li;
            const float bv = bias[col];
#pragma unroll
            for (int m = 0; m < 4; ++m) {
                const long row = mBase + wr * 64 + m * 16 + lg * 4;
#pragma unroll
                for (int i = 0; i < 4; ++i)
                    Cb[(row + i) * N + col] = __float2bfloat16(acc[m][n][i] + bv);
            }
        }
    }
}

// ---------------------------------------------------------------------------
// Fused per-head RMSNorm + RoPE, in place.
// ---------------------------------------------------------------------------
__global__ __launch_bounds__(256) void norm_rope_kernel(
    bf16* __restrict__ T, const float* __restrict__ wgt,
    const float* __restrict__ cosT, const float* __restrict__ sinT,
    float scale)
{
    const int row = blockIdx.x * 256 + threadIdx.x;
    const int tok = row >> 4;
    const int h = row & 15;
    const int spos = tok & 1023;
    bf16* p = T + (size_t)tok * 1536 + h * 96;

    float x[96];
#pragma unroll
    for (int v = 0; v < 12; ++v) {
        short8 t = *(const short8*)(p + v * 8);
#pragma unroll
        for (int j = 0; j < 8; ++j) x[v * 8 + j] = b2f(t[j]);
    }
    float ss = 0.f;
#pragma unroll
    for (int d = 0; d < 96; ++d) ss += x[d] * x[d];
    const float rn = scale / sqrtf(ss * (1.0f / 96.0f) + 1e-6f);

    const float* cr = cosT + spos * 96;
    const float* sr = sinT + spos * 96;

#pragma unroll
    for (int v = 0; v < 12; ++v) {
        short8 o;
#pragma unroll
        for (int j = 0; j < 8; j += 2) {
            const int d = v * 8 + j;
            const float x0 = x[d] * rn * wgt[d];
            const float x1 = x[d + 1] * rn * wgt[d + 1];
            o[j]     = f2b(x0 * cr[d] - x1 * sr[d]);
            o[j + 1] = f2b(x1 * cr[d + 1] + x0 * sr[d + 1]);
        }
        *(short8*)(p + v * 8) = o;
    }
}

// ---------------------------------------------------------------------------
// Flash attention v2: block = (b,h) x 128 Q rows (4 waves x 32). KV tile 64.
// K tile LDS [64][100] (conflict-free b128 reads), V^T LDS [96][76] (2-way),
// per-wave P [32][72] (2-way). Coalesced staging; XCD-chunked block swizzle.
// ---------------------------------------------------------------------------
__global__ __launch_bounds__(256) void attn_kernel(
    const bf16* __restrict__ Q, const bf16* __restrict__ K,
    const bf16* __restrict__ V, bf16* __restrict__ O)
{
    __shared__ __align__(16) short Ks[64 * 100];
    __shared__ __align__(16) short Vt[96 * 76];
    __shared__ __align__(16) short Pl[4][32 * 72];

    const int tid = threadIdx.x;
    const int l = tid & 63, w = tid >> 6;
    const int li = l & 15, lg = l >> 4;

    // XCD-chunked swizzle: 1024 blocks, 8 XCDs; the 8 q-tiles of one (b,h)
    // land on one XCD -> K/V L2 reuse.
    const int p = blockIdx.x;
    const int lb = (p & 7) * 128 + (p >> 3);
    const int qt = lb & 7;
    const int bh = lb >> 3;
    const int b = bh >> 4, h = bh & 15;
    const size_t tokBase = (size_t)b * 1024;

    // Q fragments: rows qt*128 + w*32 + r*16 + li (scale pre-folded into Q)
    short8 aq[2][3];
#pragma unroll
    for (int r = 0; r < 2; ++r) {
        const bf16* qp = Q + (tokBase + qt * 128 + w * 32 + r * 16 + li) * 1536 + h * 96;
#pragma unroll
        for (int kk = 0; kk < 3; ++kk)
            aq[r][kk] = *(const short8*)(qp + kk * 32 + lg * 8);
    }

    float m_r[2][4], l_r[2][4];
#pragma unroll
    for (int r = 0; r < 2; ++r)
#pragma unroll
        for (int i = 0; i < 4; ++i) { m_r[r][i] = -1e30f; l_r[r][i] = 0.f; }
    f32x4 o[2][6] = {};

    // K staging map: 768 16B-chunks, 3 per thread (constant across tiles)
    int kr[3], km[3];
#pragma unroll
    for (int u = 0; u < 3; ++u) {
        const int c = tid + 256 * u;
        kr[u] = c / 12;
        km[u] = (c - kr[u] * 12) * 8;
    }
    const int vr = tid >> 2;
    const int vc0 = (tid & 3) * 24;
    short* Plw = &Pl[w][0];

    for (int t0 = 0; t0 < 1024; t0 += 64) {
        __syncthreads();  // prior tile's QK/PV reads of Ks/Vt complete
        // stage K [64][100]
#pragma unroll
        for (int u = 0; u < 3; ++u) {
            short8 t = *(const short8*)(K + (tokBase + t0 + kr[u]) * 1536 + h * 96 + km[u]);
            *(short8*)&Ks[kr[u] * 100 + km[u]] = t;
        }
        // stage V^T [96][76]
        const bf16* vp = V + (tokBase + t0 + vr) * 1536 + h * 96 + vc0;
#pragma unroll
        for (int u = 0; u < 3; ++u) {
            short8 t = *(const short8*)(vp + u * 8);
#pragma unroll
            for (int j = 0; j < 8; ++j)
                Vt[(vc0 + u * 8 + j) * 76 + vr] = t[j];
        }
        __syncthreads();

        // QK^T: S[32][64] per wave
        f32x4 s4[2][4] = {};
#pragma unroll
        for (int kk = 0; kk < 3; ++kk) {
            short8 fb[4];
#pragma unroll
            for (int kn = 0; kn < 4; ++kn)
                fb[kn] = *(const short8*)&Ks[(kn * 16 + li) * 100 + kk * 32 + lg * 8];
#pragma unroll
            for (int r = 0; r < 2; ++r)
#pragma unroll
                for (int kn = 0; kn < 4; ++kn)
                    s4[r][kn] = MFMA16(aq[r][kk], fb[kn], s4[r][kn]);
        }

        // online softmax rows q = r*16 + lg*4 + i (reduce over li)
#pragma unroll
        for (int r = 0; r < 2; ++r)
#pragma unroll
            for (int i = 0; i < 4; ++i) {
                float pm = fmaxf(fmaxf(s4[r][0][i], s4[r][1][i]),
                                 fmaxf(s4[r][2][i], s4[r][3][i]));
#pragma unroll
                for (int msk = 1; msk < 16; msk <<= 1)
                    pm = fmaxf(pm, __shfl_xor(pm, msk));
                const float mn = fmaxf(m_r[r][i], pm);
                const float alpha = __expf(m_r[r][i] - mn);
                m_r[r][i] = mn;
                float rs = 0.f;
#pragma unroll
                for (int kn = 0; kn < 4; ++kn) {
                    const float pv = __expf(s4[r][kn][i] - mn);
                    rs += pv;
                    Plw[(r * 16 + lg * 4 + i) * 72 + kn * 16 + li] = f2b(pv);
                }
#pragma unroll
                for (int msk = 1; msk < 16; msk <<= 1)
                    rs += __shfl_xor(rs, msk);
                l_r[r][i] = l_r[r][i] * alpha + rs;
#pragma unroll
                for (int dn = 0; dn < 6; ++dn) o[r][dn][i] *= alpha;
            }

        // PV: o += P @ V  (same-wave ds_write->ds_read, compiler waits lgkm)
#pragma unroll
        for (int kt = 0; kt < 2; ++kt) {
            short8 pa[2];
#pragma unroll
            for (int r = 0; r < 2; ++r)
                pa[r] = *(const short8*)&Plw[(r * 16 + li) * 72 + kt * 32 + lg * 8];
#pragma unroll
            for (int dn = 0; dn < 6; ++dn) {
                short8 fv = *(const short8*)&Vt[(dn * 16 + li) * 76 + kt * 32 + lg * 8];
#pragma unroll
                for (int r = 0; r < 2; ++r)
                    o[r][dn] = MFMA16(pa[r], fv, o[r][dn]);
            }
        }
    }

#pragma unroll
    for (int r = 0; r < 2; ++r)
#pragma unroll
        for (int dn = 0; dn < 6; ++dn)
#pragma unroll
            for (int i = 0; i < 4; ++i) {
                const size_t row = tokBase + qt * 128 + w * 32 + r * 16 + lg * 4 + i;
                O[row * 1536 + h * 96 + dn * 16 + li] =
                    __float2bfloat16(o[r][dn][i] / l_r[r][i]);
            }
}

// ---------------------------------------------------------------------------
extern "C" void kernel_launch(void* const* d_in, const int* in_sizes, int n_in,
                              void* d_out, int out_size, void* d_ws, size_t ws_size,
                              hipStream_t stream) {
    const void* X  = d_in[0];
    const void* Wq = d_in[1];
    const void* bq = d_in[2];
    const void* Wk = d_in[3];
    const void* bk = d_in[4];
    const void* Wv = d_in[5];
    const void* bv = d_in[6];
    const void* qw = d_in[7];
    const void* kw = d_in[8];
    const void* Wo = d_in[9];
    const void* bo = d_in[10];

    char* ws = (char*)d_ws;
    size_t off = 0;
    int* flag = (int*)ws;                      off += 256;
    float* cosT = (float*)(ws + off);          off += 1024 * 96 * 4;
    float* sinT = (float*)(ws + off);          off += 1024 * 96 * 4;
    float* bqc  = (float*)(ws + off);          off += 1536 * 4;
    float* bkc  = (float*)(ws + off);          off += 1536 * 4;
    float* bvc  = (float*)(ws + off);          off += 1536 * 4;
    float* boc  = (float*)(ws + off);          off += 1536 * 4;
    float* qwc  = (float*)(ws + off);          off += 128 * 4;
    float* kwc  = (float*)(ws + off);          off += 128 * 4;
    off = (off + 255) & ~(size_t)255;
    bf16* Wqc = (bf16*)(ws + off);             off += (size_t)1536 * 1536 * 2;
    bf16* Wkc = (bf16*)(ws + off);             off += (size_t)1536 * 1536 * 2;
    bf16* Wvc = (bf16*)(ws + off);             off += (size_t)1536 * 1536 * 2;
    bf16* Woc = (bf16*)(ws + off);             off += (size_t)1536 * 1536 * 2;
    bf16* Xc  = (bf16*)(ws + off);             off += (size_t)8192 * 1536 * 2;  // reused as AO
    bf16* Qb  = (bf16*)(ws + off);             off += (size_t)8192 * 1536 * 2;
    bf16* Kb  = (bf16*)(ws + off);             off += (size_t)8192 * 1536 * 2;
    bf16* Vb  = (bf16*)(ws + off);             off += (size_t)8192 * 1536 * 2;
    bf16* AO  = Xc;

    sniff_kernel<<<1, 64, 0, stream>>>((const unsigned*)X, flag);

    const int nX8 = 8192 * 1536 / 8, nW8 = 1536 * 1536 / 8;
    canon_bf16_kernel<<<(nX8 + 255) / 256, 256, 0, stream>>>(X,  (short*)Xc,  nX8, flag);
    canon_bf16_kernel<<<(nW8 + 255) / 256, 256, 0, stream>>>(Wq, (short*)Wqc, nW8, flag);
    canon_bf16_kernel<<<(nW8 + 255) / 256, 256, 0, stream>>>(Wk, (short*)Wkc, nW8, flag);
    canon_bf16_kernel<<<(nW8 + 255) / 256, 256, 0, stream>>>(Wv, (short*)Wvc, nW8, flag);
    canon_bf16_kernel<<<(nW8 + 255) / 256, 256, 0, stream>>>(Wo, (short*)Woc, nW8, flag);
    canon_f32_kernel<<<6, 256, 0, stream>>>(bq, bqc, 1536, flag);
    canon_f32_kernel<<<6, 256, 0, stream>>>(bk, bkc, 1536, flag);
    canon_f32_kernel<<<6, 256, 0, stream>>>(bv, bvc, 1536, flag);
    canon_f32_kernel<<<6, 256, 0, stream>>>(bo, boc, 1536, flag);
    canon_f32_kernel<<<1, 256, 0, stream>>>(qw, qwc, 96, flag);
    canon_f32_kernel<<<1, 256, 0, stream>>>(kw, kwc, 96, flag);

    rope_tables_kernel<<<384, 256, 0, stream>>>(cosT, sinT);

    gemm_bias_kernel<<<dim3(12, 64), 256, 0, stream>>>(Xc, Wqc, bqc, Qb, 8192, 1536, 1536, nullptr);
    gemm_bias_kernel<<<dim3(12, 64), 256, 0, stream>>>(Xc, Wkc, bkc, Kb, 8192, 1536, 1536, nullptr);
    gemm_bias_kernel<<<dim3(12, 64), 256, 0, stream>>>(Xc, Wvc, bvc, Vb, 8192, 1536, 1536, nullptr);

    norm_rope_kernel<<<512, 256, 0, stream>>>(Qb, qwc, cosT, sinT, 0.10206207261596577f);
    norm_rope_kernel<<<512, 256, 0, stream>>>(Kb, kwc, cosT, sinT, 1.0f);

    attn_kernel<<<1024, 256, 0, stream>>>(Qb, Kb, Vb, AO);

    gemm_bias_kernel<<<dim3(12, 64), 256, 0, stream>>>(AO, Woc, boc, d_out, 8192, 1536, 1536, flag);
}

// Round 4
// 497.651 us; speedup vs baseline: 1.3601x; 1.0566x over previous
//
#include <hip/hip_runtime.h>
#include <hip/hip_bf16.h>
#include <math.h>

typedef __hip_bfloat16 bf16;
typedef __attribute__((ext_vector_type(8))) short short8;
typedef __attribute__((ext_vector_type(4))) float f32x4;

#define MFMA16(a, b, c) __builtin_amdgcn_mfma_f32_16x16x32_bf16((a), (b), (c), 0, 0, 0)

typedef const __attribute__((address_space(1))) void GVOID;
typedef __attribute__((address_space(3))) void LVOID;

__device__ __forceinline__ float b2f(short s) {
    union { unsigned u; float f; } v;
    v.u = ((unsigned)(unsigned short)s) << 16;
    return v.f;
}
__device__ __forceinline__ short f2b(float f) {
    union { float f; unsigned u; } v;
    v.f = f;
    unsigned r = v.u + 0x7fffu + ((v.u >> 16) & 1u);
    return (short)(r >> 16);
}

// ---------------------------------------------------------------------------
// Dtype sniffer (f32 vs bf16 inputs) — confirmed f32 in rounds 2/3, kept as guard.
// ---------------------------------------------------------------------------
__global__ void sniff_kernel(const unsigned* __restrict__ X, int* __restrict__ flag) {
    __shared__ int cnt;
    if (threadIdx.x == 0) cnt = 0;
    __syncthreads();
    int c = 0;
    for (int i = threadIdx.x; i < 256; i += 64) {
        unsigned w = X[i];
        unsigned e = (w >> 7) & 0xFFu;
        c += (e > 140u) ? 1 : 0;
    }
    atomicAdd(&cnt, c);
    __syncthreads();
    if (threadIdx.x == 0) *flag = (cnt >= 16) ? 1 : 0;
}

__device__ __forceinline__ void canon8(const void* src, short* dst, int i, int f) {
    short8 o;
    if (f) {
        const float* s = (const float*)src + (size_t)i * 8;
#pragma unroll
        for (int j = 0; j < 8; ++j) o[j] = f2b(s[j]);
    } else {
        o = ((const short8*)src)[i];
    }
    ((short8*)dst)[i] = o;
}

__global__ __launch_bounds__(256) void canon_x_kernel(
    const void* __restrict__ src, short* __restrict__ dst, int n8,
    const int* __restrict__ flag)
{
    int i = blockIdx.x * 256 + threadIdx.x;
    if (i >= n8) return;
    canon8(src, dst, i, *flag);
}

// 4 weight matrices in one dispatch; dst0..2 are contiguous rows of Wqkv.
__global__ __launch_bounds__(256) void canon_w4_kernel(
    const void* __restrict__ s0, const void* __restrict__ s1,
    const void* __restrict__ s2, const void* __restrict__ s3,
    short* __restrict__ d0, short* __restrict__ d1,
    short* __restrict__ d2, short* __restrict__ d3,
    const int* __restrict__ flag)
{
    const int m = blockIdx.y;
    const void* src = (m == 0) ? s0 : (m == 1) ? s1 : (m == 2) ? s2 : s3;
    short* dst = (m == 0) ? d0 : (m == 1) ? d1 : (m == 2) ? d2 : d3;
    int i = blockIdx.x * 256 + threadIdx.x;  // 1152 blocks -> 294912 groups
    canon8(src, dst, i, *flag);
}

// All small vectors: biasqkv[4608] <- bq|bk|bv, bo[1536], qw[96], kw[96].
__global__ void canon_vec_kernel(
    const void* __restrict__ bq, const void* __restrict__ bk,
    const void* __restrict__ bv, const void* __restrict__ bo,
    const void* __restrict__ qw, const void* __restrict__ kw,
    float* __restrict__ biasqkv, float* __restrict__ boc,
    float* __restrict__ qwc, float* __restrict__ kwc,
    const int* __restrict__ flag)
{
    const int f = *flag;
    for (int i = threadIdx.x; i < 6336; i += 256) {
        const void* src; float* dst; int j;
        if (i < 4608) {
            int m = i / 1536; j = i - m * 1536;
            src = (m == 0) ? bq : (m == 1) ? bk : bv; dst = biasqkv + i;
        } else if (i < 6144) { j = i - 4608; src = bo; dst = boc + j; }
        else if (i < 6240)   { j = i - 6144; src = qw; dst = qwc + j; }
        else                 { j = i - 6240; src = kw; dst = kwc + j; }
        *dst = f ? ((const float*)src)[j] : b2f(((const short*)src)[j]);
    }
}

// ---------------------------------------------------------------------------
// RoPE tables: cos/sin [1024][96] fp32.
// ---------------------------------------------------------------------------
__global__ void rope_tables_kernel(float* __restrict__ cosT, float* __restrict__ sinT) {
    int idx = blockIdx.x * 256 + threadIdx.x;
    if (idx >= 1024 * 96) return;
    int p = idx / 96;
    int d = idx - p * 96;
    int r = p >> 5, c = p & 31;
    int inRow = (d < 48);
    int dd = inRow ? d : d - 48;
    float pos = inRow ? (float)r : (float)c;
    float ex = -(float)(dd & ~1) / 48.0f;
    float f = powf(10000.0f, ex);
    float ang = pos * f;
    cosT[idx] = cosf(ang);
    sinT[idx] = sinf(ang);
}

// ---------------------------------------------------------------------------
// Pipelined NT GEMM + bias: C = A[M,K] * B[N,K]^T + bias. Double-buffered LDS
// (T3 minimal 2-phase: stage t+1, compute t, one barrier/iter). 128x128 tile,
// BK=32. 3-way output split (QKV fused; mat = nb/12). XCD-chunked swizzle.
// ---------------------------------------------------------------------------
__global__ __launch_bounds__(256) void gemm_db_kernel(
    const bf16* __restrict__ A, const bf16* __restrict__ Bw,
    const float* __restrict__ bias,
    bf16* __restrict__ O0, bf16* __restrict__ O1, bf16* __restrict__ O2,
    int K, const int* __restrict__ outFlag)
{
    __shared__ __align__(16) short As[2][128 * 32];
    __shared__ __align__(16) short Bs[2][128 * 32];

    const int tid = threadIdx.x;
    const int l = tid & 63, w = tid >> 6;
    const int wr = w >> 1, wc = w & 1;
    const int li = l & 15, lg = l >> 4;

    // XCD-chunked swizzle (total % 8 == 0 for both grids -> bijective)
    const int total = gridDim.x * gridDim.y;
    const int p = blockIdx.y * gridDim.x + blockIdx.x;
    const int lb = (p & 7) * (total >> 3) + (p >> 3);
    const int nb = lb % gridDim.x;
    const int mb = lb / gridDim.x;

    const int mat = nb / 12;                       // 0..2 (0 for N=1536 grids)
    const long nGlob = (long)nb * 128;             // row into Bw / bias
    const long nLoc = (long)(nb - mat * 12) * 128; // col into output (N=1536)
    const long mBase = (long)mb * 128;

    const int srow = tid >> 2;
    const int scol = (tid & 3) * 8;
    const bf16* ga0 = A + (mBase + srow) * K + scol;
    const bf16* ga1 = ga0 + (long)64 * K;
    const bf16* gb0 = Bw + (nGlob + srow) * K + scol;
    const bf16* gb1 = gb0 + (long)64 * K;
    const int lo = srow * 32 + scol;
    const int lo1 = 64 * 32 + lo;

    f32x4 acc[4][4] = {};

    __builtin_amdgcn_global_load_lds((GVOID*)ga0, (LVOID*)&As[0][lo], 16, 0, 0);
    __builtin_amdgcn_global_load_lds((GVOID*)ga1, (LVOID*)&As[0][lo1], 16, 0, 0);
    __builtin_amdgcn_global_load_lds((GVOID*)gb0, (LVOID*)&Bs[0][lo], 16, 0, 0);
    __builtin_amdgcn_global_load_lds((GVOID*)gb1, (LVOID*)&Bs[0][lo1], 16, 0, 0);
    __syncthreads();

    int cur = 0;
    for (int k0 = 32; k0 < K; k0 += 32) {
        const int nxt = cur ^ 1;
        __builtin_amdgcn_global_load_lds((GVOID*)(ga0 + k0), (LVOID*)&As[nxt][lo], 16, 0, 0);
        __builtin_amdgcn_global_load_lds((GVOID*)(ga1 + k0), (LVOID*)&As[nxt][lo1], 16, 0, 0);
        __builtin_amdgcn_global_load_lds((GVOID*)(gb0 + k0), (LVOID*)&Bs[nxt][lo], 16, 0, 0);
        __builtin_amdgcn_global_load_lds((GVOID*)(gb1 + k0), (LVOID*)&Bs[nxt][lo1], 16, 0, 0);

        short8 fa[4], fb[4];
#pragma unroll
        for (int m = 0; m < 4; ++m)
            fa[m] = *(const short8*)&As[cur][(wr * 64 + m * 16 + li) * 32 + lg * 8];
#pragma unroll
        for (int n = 0; n < 4; ++n)
            fb[n] = *(const short8*)&Bs[cur][(wc * 64 + n * 16 + li) * 32 + lg * 8];
#pragma unroll
        for (int m = 0; m < 4; ++m)
#pragma unroll
            for (int n = 0; n < 4; ++n)
                acc[m][n] = MFMA16(fa[m], fb[n], acc[m][n]);
        __syncthreads();   // implicit vmcnt(0): next tile staged; reads of cur done
        cur = nxt;
    }
    {
        short8 fa[4], fb[4];
#pragma unroll
        for (int m = 0; m < 4; ++m)
            fa[m] = *(const short8*)&As[cur][(wr * 64 + m * 16 + li) * 32 + lg * 8];
#pragma unroll
        for (int n = 0; n < 4; ++n)
            fb[n] = *(const short8*)&Bs[cur][(wc * 64 + n * 16 + li) * 32 + lg * 8];
#pragma unroll
        for (int m = 0; m < 4; ++m)
#pragma unroll
            for (int n = 0; n < 4; ++n)
                acc[m][n] = MFMA16(fa[m], fb[n], acc[m][n]);
    }

    const int f32out = outFlag ? *outFlag : 0;
    bf16* Ob = (mat == 0) ? O0 : (mat == 1) ? O1 : O2;
    if (f32out) {
        float* Cf = (float*)Ob;
#pragma unroll
        for (int n = 0; n < 4; ++n) {
            const long col = nLoc + wc * 64 + n * 16 + li;
            const float bv = bias[nGlob + wc * 64 + n * 16 + li];
#pragma unroll
            for (int m = 0; m < 4; ++m) {
                const long row = mBase + wr * 64 + m * 16 + lg * 4;
#pragma unroll
                for (int i = 0; i < 4; ++i)
                    Cf[(row + i) * 1536 + col] = acc[m][n][i] + bv;
            }
        }
    } else {
#pragma unroll
        for (int n = 0; n < 4; ++n) {
            const long col = nLoc + wc * 64 + n * 16 + li;
            const float bv = bias[nGlob + wc * 64 + n * 16 + li];
#pragma unroll
            for (int m = 0; m < 4; ++m) {
                const long row = mBase + wr * 64 + m * 16 + lg * 4;
#pragma unroll
                for (int i = 0; i < 4; ++i)
                    Ob[(row + i) * 1536 + col] = __float2bfloat16(acc[m][n][i] + bv);
            }
        }
    }
}

// ---------------------------------------------------------------------------
// Fused per-head RMSNorm + RoPE, in place. scale folds 1/sqrt(96) (and log2e
// for Q, so attention can use exp2 directly).
// ---------------------------------------------------------------------------
__global__ __launch_bounds__(256) void norm_rope_kernel(
    bf16* __restrict__ T, const float* __restrict__ wgt,
    const float* __restrict__ cosT, const float* __restrict__ sinT,
    float scale)
{
    const int row = blockIdx.x * 256 + threadIdx.x;
    const int tok = row >> 4;
    const int h = row & 15;
    const int spos = tok & 1023;
    bf16* p = T + (size_t)tok * 1536 + h * 96;

    float x[96];
#pragma unroll
    for (int v = 0; v < 12; ++v) {
        short8 t = *(const short8*)(p + v * 8);
#pragma unroll
        for (int j = 0; j < 8; ++j) x[v * 8 + j] = b2f(t[j]);
    }
    float ss = 0.f;
#pragma unroll
    for (int d = 0; d < 96; ++d) ss += x[d] * x[d];
    const float rn = scale / sqrtf(ss * (1.0f / 96.0f) + 1e-6f);

    const float* cr = cosT + spos * 96;
    const float* sr = sinT + spos * 96;

#pragma unroll
    for (int v = 0; v < 12; ++v) {
        short8 o;
#pragma unroll
        for (int j = 0; j < 8; j += 2) {
            const int d = v * 8 + j;
            const float x0 = x[d] * rn * wgt[d];
            const float x1 = x[d + 1] * rn * wgt[d + 1];
            o[j]     = f2b(x0 * cr[d] - x1 * sr[d]);
            o[j + 1] = f2b(x1 * cr[d + 1] + x0 * sr[d + 1]);
        }
        *(short8*)(p + v * 8) = o;
    }
}

// ---------------------------------------------------------------------------
// Flash attention: block = (b,h) x 128 Q rows (4 waves x 32). KV tile 64.
// Scores in log2 domain (log2e folded into Q); defer-max THR=8 -> P <= 256.
// ---------------------------------------------------------------------------
__global__ __launch_bounds__(256) void attn_kernel(
    const bf16* __restrict__ Q, const bf16* __restrict__ K,
    const bf16* __restrict__ V, bf16* __restrict__ O)
{
    __shared__ __align__(16) short Ks[64 * 100];
    __shared__ __align__(16) short Vt[96 * 76];
    __shared__ __align__(16) short Pl[4][32 * 72];

    const int tid = threadIdx.x;
    const int l = tid & 63, w = tid >> 6;
    const int li = l & 15, lg = l >> 4;

    const int p = blockIdx.x;
    const int lb = (p & 7) * 128 + (p >> 3);
    const int qt = lb & 7;
    const int bh = lb >> 3;
    const int b = bh >> 4, h = bh & 15;
    const size_t tokBase = (size_t)b * 1024;

    short8 aq[2][3];
#pragma unroll
    for (int r = 0; r < 2; ++r) {
        const bf16* qp = Q + (tokBase + qt * 128 + w * 32 + r * 16 + li) * 1536 + h * 96;
#pragma unroll
        for (int kk = 0; kk < 3; ++kk)
            aq[r][kk] = *(const short8*)(qp + kk * 32 + lg * 8);
    }

    float m_r[2][4], l_r[2][4];
#pragma unroll
    for (int r = 0; r < 2; ++r)
#pragma unroll
        for (int i = 0; i < 4; ++i) { m_r[r][i] = -1e30f; l_r[r][i] = 0.f; }
    f32x4 o[2][6] = {};

    int kr[3], km[3];
#pragma unroll
    for (int u = 0; u < 3; ++u) {
        const int c = tid + 256 * u;
        kr[u] = c / 12;
        km[u] = (c - kr[u] * 12) * 8;
    }
    const int vr = tid >> 2;
    const int vc0 = (tid & 3) * 24;
    short* Plw = &Pl[w][0];

    for (int t0 = 0; t0 < 1024; t0 += 64) {
        __syncthreads();
#pragma unroll
        for (int u = 0; u < 3; ++u) {
            short8 t = *(const short8*)(K + (tokBase + t0 + kr[u]) * 1536 + h * 96 + km[u]);
            *(short8*)&Ks[kr[u] * 100 + km[u]] = t;
        }
        const bf16* vp = V + (tokBase + t0 + vr) * 1536 + h * 96 + vc0;
#pragma unroll
        for (int u = 0; u < 3; ++u) {
            short8 t = *(const short8*)(vp + u * 8);
#pragma unroll
            for (int j = 0; j < 8; ++j)
                Vt[(vc0 + u * 8 + j) * 76 + vr] = t[j];
        }
        __syncthreads();

        f32x4 s4[2][4] = {};
#pragma unroll
        for (int kk = 0; kk < 3; ++kk) {
            short8 fb[4];
#pragma unroll
            for (int kn = 0; kn < 4; ++kn)
                fb[kn] = *(const short8*)&Ks[(kn * 16 + li) * 100 + kk * 32 + lg * 8];
#pragma unroll
            for (int r = 0; r < 2; ++r)
#pragma unroll
                for (int kn = 0; kn < 4; ++kn)
                    s4[r][kn] = MFMA16(aq[r][kk], fb[kn], s4[r][kn]);
        }

#pragma unroll
        for (int r = 0; r < 2; ++r) {
            float alpha[4];
            bool need = false;
#pragma unroll
            for (int i = 0; i < 4; ++i) {
                float pm = fmaxf(fmaxf(s4[r][0][i], s4[r][1][i]),
                                 fmaxf(s4[r][2][i], s4[r][3][i]));
#pragma unroll
                for (int msk = 1; msk < 16; msk <<= 1)
                    pm = fmaxf(pm, __shfl_xor(pm, msk));
                const float mo = m_r[r][i];
                if (pm > mo + 8.0f) {            // defer-max: P bounded by 2^8
                    alpha[i] = exp2f(mo - pm);
                    m_r[r][i] = pm;
                    need = true;
                } else {
                    alpha[i] = 1.0f;
                }
                const float mn = m_r[r][i];
                float rs = 0.f;
#pragma unroll
                for (int kn = 0; kn < 4; ++kn) {
                    const float pv = exp2f(s4[r][kn][i] - mn);
                    rs += pv;
                    Plw[(r * 16 + lg * 4 + i) * 72 + kn * 16 + li] = f2b(pv);
                }
#pragma unroll
                for (int msk = 1; msk < 16; msk <<= 1)
                    rs += __shfl_xor(rs, msk);
                l_r[r][i] = l_r[r][i] * alpha[i] + rs;
            }
            if (need) {
#pragma unroll
                for (int dn = 0; dn < 6; ++dn)
#pragma unroll
                    for (int i = 0; i < 4; ++i) o[r][dn][i] *= alpha[i];
            }
        }

#pragma unroll
        for (int kt = 0; kt < 2; ++kt) {
            short8 pa[2];
#pragma unroll
            for (int r = 0; r < 2; ++r)
                pa[r] = *(const short8*)&Plw[(r * 16 + li) * 72 + kt * 32 + lg * 8];
#pragma unroll
            for (int dn = 0; dn < 6; ++dn) {
                short8 fv = *(const short8*)&Vt[(dn * 16 + li) * 76 + kt * 32 + lg * 8];
#pragma unroll
                for (int r = 0; r < 2; ++r)
                    o[r][dn] = MFMA16(pa[r], fv, o[r][dn]);
            }
        }
    }

#pragma unroll
    for (int r = 0; r < 2; ++r)
#pragma unroll
        for (int dn = 0; dn < 6; ++dn)
#pragma unroll
            for (int i = 0; i < 4; ++i) {
                const size_t row = tokBase + qt * 128 + w * 32 + r * 16 + lg * 4 + i;
                O[row * 1536 + h * 96 + dn * 16 + li] =
                    __float2bfloat16(o[r][dn][i] / l_r[r][i]);
            }
}

// ---------------------------------------------------------------------------
extern "C" void kernel_launch(void* const* d_in, const int* in_sizes, int n_in,
                              void* d_out, int out_size, void* d_ws, size_t ws_size,
                              hipStream_t stream) {
    const void* X  = d_in[0];
    const void* Wq = d_in[1];
    const void* bq = d_in[2];
    const void* Wk = d_in[3];
    const void* bk = d_in[4];
    const void* Wv = d_in[5];
    const void* bv = d_in[6];
    const void* qw = d_in[7];
    const void* kw = d_in[8];
    const void* Wo = d_in[9];
    const void* bo = d_in[10];

    char* ws = (char*)d_ws;
    size_t off = 0;
    int* flag = (int*)ws;                      off += 256;
    float* cosT = (float*)(ws + off);          off += 1024 * 96 * 4;
    float* sinT = (float*)(ws + off);          off += 1024 * 96 * 4;
    float* biasqkv = (float*)(ws + off);       off += 4608 * 4;
    float* boc  = (float*)(ws + off);          off += 1536 * 4;
    float* qwc  = (float*)(ws + off);          off += 128 * 4;
    float* kwc  = (float*)(ws + off);          off += 128 * 4;
    off = (off + 255) & ~(size_t)255;
    bf16* Wc  = (bf16*)(ws + off);             off += (size_t)4608 * 1536 * 2;  // Wq|Wk|Wv rows
    bf16* Woc = (bf16*)(ws + off);             off += (size_t)1536 * 1536 * 2;
    bf16* Xc  = (bf16*)(ws + off);             off += (size_t)8192 * 1536 * 2;  // reused as AO
    bf16* Qb  = (bf16*)(ws + off);             off += (size_t)8192 * 1536 * 2;
    bf16* Kb  = (bf16*)(ws + off);             off += (size_t)8192 * 1536 * 2;
    bf16* Vb  = (bf16*)(ws + off);             off += (size_t)8192 * 1536 * 2;
    bf16* AO  = Xc;

    sniff_kernel<<<1, 64, 0, stream>>>((const unsigned*)X, flag);

    canon_x_kernel<<<6144, 256, 0, stream>>>(X, (short*)Xc, 8192 * 1536 / 8, flag);
    canon_w4_kernel<<<dim3(1152, 4), 256, 0, stream>>>(
        Wq, Wk, Wv, Wo,
        (short*)Wc, (short*)(Wc + (size_t)1536 * 1536), (short*)(Wc + (size_t)2 * 1536 * 1536),
        (short*)Woc, flag);
    canon_vec_kernel<<<1, 256, 0, stream>>>(bq, bk, bv, bo, qw, kw,
                                            biasqkv, boc, qwc, kwc, flag);
    rope_tables_kernel<<<384, 256, 0, stream>>>(cosT, sinT);

    // fused QKV projection: C[8192,4608] = Xc @ Wc^T + biasqkv, split to Qb/Kb/Vb
    gemm_db_kernel<<<dim3(36, 64), 256, 0, stream>>>(
        Xc, Wc, biasqkv, Qb, Kb, Vb, 1536, nullptr);

    const float qscale = (float)(0.10206207261596577 * 1.4426950408889634);  // 1/sqrt(96)*log2(e)
    norm_rope_kernel<<<512, 256, 0, stream>>>(Qb, qwc, cosT, sinT, qscale);
    norm_rope_kernel<<<512, 256, 0, stream>>>(Kb, kwc, cosT, sinT, 1.0f);

    attn_kernel<<<1024, 256, 0, stream>>>(Qb, Kb, Vb, AO);

    gemm_db_kernel<<<dim3(12, 64), 256, 0, stream>>>(
        AO, Woc, boc, (bf16*)d_out, (bf16*)d_out, (bf16*)d_out, 1536, flag);
}

// Round 5
// 434.676 us; speedup vs baseline: 1.5571x; 1.1449x over previous
//
#include <hip/hip_runtime.h>
#include <hip/hip_bf16.h>
#include <math.h>

typedef __hip_bfloat16 bf16;
typedef __attribute__((ext_vector_type(8))) short short8;
typedef __attribute__((ext_vector_type(4))) float f32x4;

#define MFMA16(a, b, c) __builtin_amdgcn_mfma_f32_16x16x32_bf16((a), (b), (c), 0, 0, 0)

typedef const __attribute__((address_space(1))) void GVOID;
typedef __attribute__((address_space(3))) void LVOID;

__device__ __forceinline__ float b2f(short s) {
    union { unsigned u; float f; } v;
    v.u = ((unsigned)(unsigned short)s) << 16;
    return v.f;
}
__device__ __forceinline__ short f2b(float f) {
    union { float f; unsigned u; } v;
    v.f = f;
    unsigned r = v.u + 0x7fffu + ((v.u >> 16) & 1u);
    return (short)(r >> 16);
}

// ---------------------------------------------------------------------------
// Dtype sniffer (f32 vs bf16 inputs) — f32 confirmed; kept as deterministic guard.
// ---------------------------------------------------------------------------
__global__ void sniff_kernel(const unsigned* __restrict__ X, int* __restrict__ flag) {
    __shared__ int cnt;
    if (threadIdx.x == 0) cnt = 0;
    __syncthreads();
    int c = 0;
    for (int i = threadIdx.x; i < 256; i += 64) {
        unsigned w = X[i];
        unsigned e = (w >> 7) & 0xFFu;
        c += (e > 140u) ? 1 : 0;
    }
    atomicAdd(&cnt, c);
    __syncthreads();
    if (threadIdx.x == 0) *flag = (cnt >= 16) ? 1 : 0;
}

__device__ __forceinline__ void canon8(const void* src, short* dst, int i, int f) {
    short8 o;
    if (f) {
        const float* s = (const float*)src + (size_t)i * 8;
#pragma unroll
        for (int j = 0; j < 8; ++j) o[j] = f2b(s[j]);
    } else {
        o = ((const short8*)src)[i];
    }
    ((short8*)dst)[i] = o;
}

__global__ __launch_bounds__(256) void canon_x_kernel(
    const void* __restrict__ src, short* __restrict__ dst, int n8,
    const int* __restrict__ flag)
{
    int i = blockIdx.x * 256 + threadIdx.x;
    if (i >= n8) return;
    canon8(src, dst, i, *flag);
}

__global__ __launch_bounds__(256) void canon_w4_kernel(
    const void* __restrict__ s0, const void* __restrict__ s1,
    const void* __restrict__ s2, const void* __restrict__ s3,
    short* __restrict__ d0, short* __restrict__ d1,
    short* __restrict__ d2, short* __restrict__ d3,
    const int* __restrict__ flag)
{
    const int m = blockIdx.y;
    const void* src = (m == 0) ? s0 : (m == 1) ? s1 : (m == 2) ? s2 : s3;
    short* dst = (m == 0) ? d0 : (m == 1) ? d1 : (m == 2) ? d2 : d3;
    int i = blockIdx.x * 256 + threadIdx.x;
    canon8(src, dst, i, *flag);
}

__global__ void canon_vec_kernel(
    const void* __restrict__ bq, const void* __restrict__ bk,
    const void* __restrict__ bv, const void* __restrict__ bo,
    const void* __restrict__ qw, const void* __restrict__ kw,
    float* __restrict__ biasqkv, float* __restrict__ boc,
    float* __restrict__ qwc, float* __restrict__ kwc,
    const int* __restrict__ flag)
{
    const int f = *flag;
    for (int i = threadIdx.x; i < 6336; i += 256) {
        const void* src; float* dst; int j;
        if (i < 4608) {
            int m = i / 1536; j = i - m * 1536;
            src = (m == 0) ? bq : (m == 1) ? bk : bv; dst = biasqkv + i;
        } else if (i < 6144) { j = i - 4608; src = bo; dst = boc + j; }
        else if (i < 6240)   { j = i - 6144; src = qw; dst = qwc + j; }
        else                 { j = i - 6240; src = kw; dst = kwc + j; }
        *dst = f ? ((const float*)src)[j] : b2f(((const short*)src)[j]);
    }
}

// ---------------------------------------------------------------------------
// RoPE tables: cos/sin [1024][96] fp32.
// ---------------------------------------------------------------------------
__global__ void rope_tables_kernel(float* __restrict__ cosT, float* __restrict__ sinT) {
    int idx = blockIdx.x * 256 + threadIdx.x;
    if (idx >= 1024 * 96) return;
    int p = idx / 96;
    int d = idx - p * 96;
    int r = p >> 5, c = p & 31;
    int inRow = (d < 48);
    int dd = inRow ? d : d - 48;
    float pos = inRow ? (float)r : (float)c;
    float ex = -(float)(dd & ~1) / 48.0f;
    float f = powf(10000.0f, ex);
    float ang = pos * f;
    cosT[idx] = cosf(ang);
    sinT[idx] = sinf(ang);
}

// ---------------------------------------------------------------------------
// 256x256 deep-pipelined NT GEMM: C = A[M,K]*B[N,K]^T + bias.
// 512 thr (8 waves 2Mx4N, 128x64 C each), BK=64, LDS 128KB dbuf.
// Full next-tile prefetch at tile start (8x global_load_lds w16); ONE
// vmcnt(0)+s_barrier per K-tile; 4 phases x {ds_read quadrant, setprio(1),
// 16 MFMA}. LDS XOR-swizzle S(x)=x^(((x>>7)&7)<<4): linear LDS dest,
// inverse-swizzled global source, swizzled ds_read (rule: both sides).
// ---------------------------------------------------------------------------
__global__ __launch_bounds__(512) void gemm256_kernel(
    const bf16* __restrict__ A, const bf16* __restrict__ Bw,
    const float* __restrict__ bias,
    bf16* __restrict__ O0, bf16* __restrict__ O1, bf16* __restrict__ O2,
    int K, const int* __restrict__ outFlag)
{
    __shared__ __align__(16) short As[2][256 * 64];
    __shared__ __align__(16) short Bs[2][256 * 64];

    const int tid = threadIdx.x;
    const int lane = tid & 63, w = tid >> 6;
    const int wm = w >> 2, wn = w & 3;
    const int li = lane & 15, lg = lane >> 4;

    // XCD-chunked bijective swizzle (total % 8 == 0)
    const int total = gridDim.x * gridDim.y;
    const int pp = blockIdx.y * gridDim.x + blockIdx.x;
    const int lb = (pp & 7) * (total >> 3) + (pp >> 3);
    const int nb = lb % gridDim.x;
    const int mb = lb / gridDim.x;
    const long mBase = (long)mb * 256;
    const long nGlob = (long)nb * 256;

    // staging maps: LDS linear dest, global source pre-swizzled
    const bf16* aSrc[4]; const bf16* bSrc[4]; int ldsOff[4];
#pragma unroll
    for (int u = 0; u < 4; ++u) {
        const int L = u * 8192 + tid * 16;          // linear byte off in 32KB tile
        const int S = L ^ (((L >> 7) & 7) << 4);    // logical source byte (involution)
        const int srow = S >> 7;
        const int scol = (S & 127) >> 1;
        aSrc[u] = A + (mBase + srow) * K + scol;
        bSrc[u] = Bw + (nGlob + srow) * K + scol;
        ldsOff[u] = L >> 1;
    }

    // fragment-read k offsets, pre-XOR'd with per-lane swizzle constant
    const int rxor = (li & 7) << 4;
    int kidx[2];
#pragma unroll
    for (int ks = 0; ks < 2; ++ks)
        kidx[ks] = ((ks * 64 + lg * 16) ^ rxor) >> 1;

    f32x4 acc[8][4] = {};
    const int NT = K >> 6;

    auto stage = [&](int tt, int bb) {
        const long kc = (long)tt * 64;
#pragma unroll
        for (int u = 0; u < 4; ++u)
            __builtin_amdgcn_global_load_lds((GVOID*)(aSrc[u] + kc),
                                             (LVOID*)&As[bb][ldsOff[u]], 16, 0, 0);
#pragma unroll
        for (int u = 0; u < 4; ++u)
            __builtin_amdgcn_global_load_lds((GVOID*)(bSrc[u] + kc),
                                             (LVOID*)&Bs[bb][ldsOff[u]], 16, 0, 0);
    };

    stage(0, 0);
    asm volatile("s_waitcnt vmcnt(0)" ::: "memory");
    __builtin_amdgcn_s_barrier();
    asm volatile("" ::: "memory");

    for (int t = 0; t < NT; ++t) {
        const int cb = t & 1;
        if (t + 1 < NT) stage(t + 1, cb ^ 1);   // full-tile prefetch, ~4 phases of cover
        const short* Ab = &As[cb][0];
        const short* Bb = &Bs[cb][0];
        short8 fa[4][2], fb[2][2];
#pragma unroll
        for (int ph = 0; ph < 4; ++ph) {
            const int qm = ph >> 1, qn = ph & 1;
            if (qn == 0) {
#pragma unroll
                for (int m = 0; m < 4; ++m) {
                    const int row = wm * 128 + (qm * 4 + m) * 16 + li;
#pragma unroll
                    for (int ks = 0; ks < 2; ++ks)
                        fa[m][ks] = *(const short8*)(Ab + row * 64 + kidx[ks]);
                }
            }
#pragma unroll
            for (int n = 0; n < 2; ++n) {
                const int row = wn * 64 + (qn * 2 + n) * 16 + li;
#pragma unroll
                for (int ks = 0; ks < 2; ++ks)
                    fb[n][ks] = *(const short8*)(Bb + row * 64 + kidx[ks]);
            }
            __builtin_amdgcn_sched_barrier(0);
            __builtin_amdgcn_s_setprio(1);
#pragma unroll
            for (int m = 0; m < 4; ++m)
#pragma unroll
                for (int n = 0; n < 2; ++n)
#pragma unroll
                    for (int ks = 0; ks < 2; ++ks)
                        acc[qm * 4 + m][qn * 2 + n] =
                            MFMA16(fa[m][ks], fb[n][ks], acc[qm * 4 + m][qn * 2 + n]);
            __builtin_amdgcn_s_setprio(0);
            __builtin_amdgcn_sched_barrier(0);
        }
        asm volatile("s_waitcnt vmcnt(0)" ::: "memory");
        __builtin_amdgcn_s_barrier();
        asm volatile("" ::: "memory");
    }

    const int f32out = outFlag ? *outFlag : 0;
    const int mat = nb / 6;                      // QKV: 6 n-tiles per matrix
    const long colBase = nGlob - (long)mat * 1536;
    bf16* Ob = (mat == 0) ? O0 : (mat == 1) ? O1 : O2;
    if (f32out) {
        float* Cf = (float*)Ob;
#pragma unroll
        for (int n = 0; n < 4; ++n) {
            const long col = colBase + wn * 64 + n * 16 + li;
            const float bv = bias[nGlob + wn * 64 + n * 16 + li];
#pragma unroll
            for (int m = 0; m < 8; ++m) {
                const long row = mBase + wm * 128 + m * 16 + lg * 4;
#pragma unroll
                for (int i = 0; i < 4; ++i)
                    Cf[(row + i) * 1536 + col] = acc[m][n][i] + bv;
            }
        }
    } else {
#pragma unroll
        for (int n = 0; n < 4; ++n) {
            const long col = colBase + wn * 64 + n * 16 + li;
            const float bv = bias[nGlob + wn * 64 + n * 16 + li];
#pragma unroll
            for (int m = 0; m < 8; ++m) {
                const long row = mBase + wm * 128 + m * 16 + lg * 4;
#pragma unroll
                for (int i = 0; i < 4; ++i)
                    Ob[(row + i) * 1536 + col] = __float2bfloat16(acc[m][n][i] + bv);
            }
        }
    }
}

// ---------------------------------------------------------------------------
// Fused per-head RMSNorm + RoPE, in place (scale folds 1/sqrt(96), +log2e for Q).
// ---------------------------------------------------------------------------
__global__ __launch_bounds__(256) void norm_rope_kernel(
    bf16* __restrict__ T, const float* __restrict__ wgt,
    const float* __restrict__ cosT, const float* __restrict__ sinT,
    float scale)
{
    const int row = blockIdx.x * 256 + threadIdx.x;
    const int tok = row >> 4;
    const int h = row & 15;
    const int spos = tok & 1023;
    bf16* p = T + (size_t)tok * 1536 + h * 96;

    float x[96];
#pragma unroll
    for (int v = 0; v < 12; ++v) {
        short8 t = *(const short8*)(p + v * 8);
#pragma unroll
        for (int j = 0; j < 8; ++j) x[v * 8 + j] = b2f(t[j]);
    }
    float ss = 0.f;
#pragma unroll
    for (int d = 0; d < 96; ++d) ss += x[d] * x[d];
    const float rn = scale / sqrtf(ss * (1.0f / 96.0f) + 1e-6f);

    const float* cr = cosT + spos * 96;
    const float* sr = sinT + spos * 96;

#pragma unroll
    for (int v = 0; v < 12; ++v) {
        short8 o;
#pragma unroll
        for (int j = 0; j < 8; j += 2) {
            const int d = v * 8 + j;
            const float x0 = x[d] * rn * wgt[d];
            const float x1 = x[d + 1] * rn * wgt[d + 1];
            o[j]     = f2b(x0 * cr[d] - x1 * sr[d]);
            o[j + 1] = f2b(x1 * cr[d + 1] + x0 * sr[d + 1]);
        }
        *(short8*)(p + v * 8) = o;
    }
}

// ---------------------------------------------------------------------------
// Flash attention: block = (b,h) x 128 Q rows (4 waves x 32). KV tile 64.
// log2-domain scores; defer-max THR=8.
// ---------------------------------------------------------------------------
__global__ __launch_bounds__(256) void attn_kernel(
    const bf16* __restrict__ Q, const bf16* __restrict__ K,
    const bf16* __restrict__ V, bf16* __restrict__ O)
{
    __shared__ __align__(16) short Ks[64 * 100];
    __shared__ __align__(16) short Vt[96 * 76];
    __shared__ __align__(16) short Pl[4][32 * 72];

    const int tid = threadIdx.x;
    const int l = tid & 63, w = tid >> 6;
    const int li = l & 15, lg = l >> 4;

    const int p = blockIdx.x;
    const int lb = (p & 7) * 128 + (p >> 3);
    const int qt = lb & 7;
    const int bh = lb >> 3;
    const int b = bh >> 4, h = bh & 15;
    const size_t tokBase = (size_t)b * 1024;

    short8 aq[2][3];
#pragma unroll
    for (int r = 0; r < 2; ++r) {
        const bf16* qp = Q + (tokBase + qt * 128 + w * 32 + r * 16 + li) * 1536 + h * 96;
#pragma unroll
        for (int kk = 0; kk < 3; ++kk)
            aq[r][kk] = *(const short8*)(qp + kk * 32 + lg * 8);
    }

    float m_r[2][4], l_r[2][4];
#pragma unroll
    for (int r = 0; r < 2; ++r)
#pragma unroll
        for (int i = 0; i < 4; ++i) { m_r[r][i] = -1e30f; l_r[r][i] = 0.f; }
    f32x4 o[2][6] = {};

    int kr[3], km[3];
#pragma unroll
    for (int u = 0; u < 3; ++u) {
        const int c = tid + 256 * u;
        kr[u] = c / 12;
        km[u] = (c - kr[u] * 12) * 8;
    }
    const int vr = tid >> 2;
    const int vc0 = (tid & 3) * 24;
    short* Plw = &Pl[w][0];

    for (int t0 = 0; t0 < 1024; t0 += 64) {
        __syncthreads();
#pragma unroll
        for (int u = 0; u < 3; ++u) {
            short8 t = *(const short8*)(K + (tokBase + t0 + kr[u]) * 1536 + h * 96 + km[u]);
            *(short8*)&Ks[kr[u] * 100 + km[u]] = t;
        }
        const bf16* vp = V + (tokBase + t0 + vr) * 1536 + h * 96 + vc0;
#pragma unroll
        for (int u = 0; u < 3; ++u) {
            short8 t = *(const short8*)(vp + u * 8);
#pragma unroll
            for (int j = 0; j < 8; ++j)
                Vt[(vc0 + u * 8 + j) * 76 + vr] = t[j];
        }
        __syncthreads();

        f32x4 s4[2][4] = {};
#pragma unroll
        for (int kk = 0; kk < 3; ++kk) {
            short8 fb[4];
#pragma unroll
            for (int kn = 0; kn < 4; ++kn)
                fb[kn] = *(const short8*)&Ks[(kn * 16 + li) * 100 + kk * 32 + lg * 8];
#pragma unroll
            for (int r = 0; r < 2; ++r)
#pragma unroll
                for (int kn = 0; kn < 4; ++kn)
                    s4[r][kn] = MFMA16(aq[r][kk], fb[kn], s4[r][kn]);
        }

#pragma unroll
        for (int r = 0; r < 2; ++r) {
            float alpha[4];
            bool need = false;
#pragma unroll
            for (int i = 0; i < 4; ++i) {
                float pm = fmaxf(fmaxf(s4[r][0][i], s4[r][1][i]),
                                 fmaxf(s4[r][2][i], s4[r][3][i]));
#pragma unroll
                for (int msk = 1; msk < 16; msk <<= 1)
                    pm = fmaxf(pm, __shfl_xor(pm, msk));
                const float mo = m_r[r][i];
                if (pm > mo + 8.0f) {
                    alpha[i] = exp2f(mo - pm);
                    m_r[r][i] = pm;
                    need = true;
                } else {
                    alpha[i] = 1.0f;
                }
                const float mn = m_r[r][i];
                float rs = 0.f;
#pragma unroll
                for (int kn = 0; kn < 4; ++kn) {
                    const float pv = exp2f(s4[r][kn][i] - mn);
                    rs += pv;
                    Plw[(r * 16 + lg * 4 + i) * 72 + kn * 16 + li] = f2b(pv);
                }
#pragma unroll
                for (int msk = 1; msk < 16; msk <<= 1)
                    rs += __shfl_xor(rs, msk);
                l_r[r][i] = l_r[r][i] * alpha[i] + rs;
            }
            if (need) {
#pragma unroll
                for (int dn = 0; dn < 6; ++dn)
#pragma unroll
                    for (int i = 0; i < 4; ++i) o[r][dn][i] *= alpha[i];
            }
        }

#pragma unroll
        for (int kt = 0; kt < 2; ++kt) {
            short8 pa[2];
#pragma unroll
            for (int r = 0; r < 2; ++r)
                pa[r] = *(const short8*)&Plw[(r * 16 + li) * 72 + kt * 32 + lg * 8];
#pragma unroll
            for (int dn = 0; dn < 6; ++dn) {
                short8 fv = *(const short8*)&Vt[(dn * 16 + li) * 76 + kt * 32 + lg * 8];
#pragma unroll
                for (int r = 0; r < 2; ++r)
                    o[r][dn] = MFMA16(pa[r], fv, o[r][dn]);
            }
        }
    }

#pragma unroll
    for (int r = 0; r < 2; ++r)
#pragma unroll
        for (int dn = 0; dn < 6; ++dn)
#pragma unroll
            for (int i = 0; i < 4; ++i) {
                const size_t row = tokBase + qt * 128 + w * 32 + r * 16 + lg * 4 + i;
                O[row * 1536 + h * 96 + dn * 16 + li] =
                    __float2bfloat16(o[r][dn][i] / l_r[r][i]);
            }
}

// ---------------------------------------------------------------------------
extern "C" void kernel_launch(void* const* d_in, const int* in_sizes, int n_in,
                              void* d_out, int out_size, void* d_ws, size_t ws_size,
                              hipStream_t stream) {
    const void* X  = d_in[0];
    const void* Wq = d_in[1];
    const void* bq = d_in[2];
    const void* Wk = d_in[3];
    const void* bk = d_in[4];
    const void* Wv = d_in[5];
    const void* bv = d_in[6];
    const void* qw = d_in[7];
    const void* kw = d_in[8];
    const void* Wo = d_in[9];
    const void* bo = d_in[10];

    char* ws = (char*)d_ws;
    size_t off = 0;
    int* flag = (int*)ws;                      off += 256;
    float* cosT = (float*)(ws + off);          off += 1024 * 96 * 4;
    float* sinT = (float*)(ws + off);          off += 1024 * 96 * 4;
    float* biasqkv = (float*)(ws + off);       off += 4608 * 4;
    float* boc  = (float*)(ws + off);          off += 1536 * 4;
    float* qwc  = (float*)(ws + off);          off += 128 * 4;
    float* kwc  = (float*)(ws + off);          off += 128 * 4;
    off = (off + 255) & ~(size_t)255;
    bf16* Wc  = (bf16*)(ws + off);             off += (size_t)4608 * 1536 * 2;
    bf16* Woc = (bf16*)(ws + off);             off += (size_t)1536 * 1536 * 2;
    bf16* Xc  = (bf16*)(ws + off);             off += (size_t)8192 * 1536 * 2;  // reused as AO
    bf16* Qb  = (bf16*)(ws + off);             off += (size_t)8192 * 1536 * 2;
    bf16* Kb  = (bf16*)(ws + off);             off += (size_t)8192 * 1536 * 2;
    bf16* Vb  = (bf16*)(ws + off);             off += (size_t)8192 * 1536 * 2;
    bf16* AO  = Xc;

    sniff_kernel<<<1, 64, 0, stream>>>((const unsigned*)X, flag);

    canon_x_kernel<<<6144, 256, 0, stream>>>(X, (short*)Xc, 8192 * 1536 / 8, flag);
    canon_w4_kernel<<<dim3(1152, 4), 256, 0, stream>>>(
        Wq, Wk, Wv, Wo,
        (short*)Wc, (short*)(Wc + (size_t)1536 * 1536), (short*)(Wc + (size_t)2 * 1536 * 1536),
        (short*)Woc, flag);
    canon_vec_kernel<<<1, 256, 0, stream>>>(bq, bk, bv, bo, qw, kw,
                                            biasqkv, boc, qwc, kwc, flag);
    rope_tables_kernel<<<384, 256, 0, stream>>>(cosT, sinT);

    // fused QKV projection: [8192,4608] = Xc @ Wc^T + biasqkv -> Qb|Kb|Vb
    gemm256_kernel<<<dim3(18, 32), 512, 0, stream>>>(
        Xc, Wc, biasqkv, Qb, Kb, Vb, 1536, nullptr);

    const float qscale = (float)(0.10206207261596577 * 1.4426950408889634);  // 1/sqrt(96)*log2(e)
    norm_rope_kernel<<<512, 256, 0, stream>>>(Qb, qwc, cosT, sinT, qscale);
    norm_rope_kernel<<<512, 256, 0, stream>>>(Kb, kwc, cosT, sinT, 1.0f);

    attn_kernel<<<1024, 256, 0, stream>>>(Qb, Kb, Vb, AO);

    gemm256_kernel<<<dim3(6, 32), 512, 0, stream>>>(
        AO, Woc, boc, (bf16*)d_out, (bf16*)d_out, (bf16*)d_out, 1536, flag);
}